// Round 1
// 665.751 us; speedup vs baseline: 1.2454x; 1.2454x over previous
//
#include <hip/hip_runtime.h>

// B=256, S=512, I=H=O=256, L=64. fp32 in/out; bf16 MFMA internally.
// This version uses OPERAND-SWAPPED MFMA everywhere: D = mfma(W_frag, a_frag)
// computes D[hidden][batch], so each lane holds 4 CONSECUTIVE hidden cols of one
// batch row -> wide b64 LDS writes / dwordx2-x4 global stores (was 16 scattered b16).
// k2/k3a use 32 wgs x 8 batch rows with COLUMN-DUPLICATED B-fragments:
//   lanes l15 and l15+8 read the same LDS address (broadcast, free) -> MFMA output
//   cols 8-15 are bitwise copies of 0-7 -> dense tanh via one cndmask merge:
//   transcendental count per step halves (32 -> 16 per lane).
typedef unsigned short u16;
typedef unsigned int   u32;
typedef __attribute__((ext_vector_type(8))) __bf16 bf16x8;
typedef __attribute__((ext_vector_type(8))) u16    u16x8;
typedef __attribute__((ext_vector_type(4))) float  f32x4;
typedef __attribute__((ext_vector_type(4))) u32    u32x4;
typedef __attribute__((ext_vector_type(2))) u32    u32x2;

#define MFMA16(a,b,c) __builtin_amdgcn_mfma_f32_16x16x32_bf16((a),(b),(c),0,0,0)
#define C_TANH 2.8853900817779268f   /* 2*log2(e): tanh(v)=1-2/(2^(C*v)+1) */
#define NL2E  -1.4426950408889634f   /* -log2(e): sigm(u)=1/(1+2^(NL2E*u)) */

__device__ __forceinline__ float ubit(u32 x){ return __builtin_bit_cast(float, x); }
__device__ __forceinline__ u16 f2b(float f){ // RNE f32->bf16 (prep paths)
    u32 b = __builtin_bit_cast(u32, f);
    b += 0x7FFFu + ((b >> 16) & 1u);
    return (u16)(b >> 16);
}
__device__ __forceinline__ u32 pkbf(float a, float b){ return ((u32)f2b(b) << 16) | (u32)f2b(a); }
__device__ __forceinline__ u32 pk_away(float a, float b){ // round-away pack (state path, matches prev numerics)
    u32 ua = (__builtin_bit_cast(u32, a) + 0x8000u) >> 16;
    u32 ub = (__builtin_bit_cast(u32, b) + 0x8000u) & 0xFFFF0000u;
    return ub | ua;
}
// Barrier that drains ONLY LDS counters -- vmem (prefetch/stores) stays in flight.
__device__ __forceinline__ void bar_lds(){ __asm__ volatile("s_waitcnt lgkmcnt(0)\n\ts_barrier" ::: "memory"); }

// ---------------- K1: xpre = C*(x@W1x + b1x + b1a), stored in k2's per-lane slot order ----------------
// xpre slot: addr_u16 = (((t*32 + bg)*4 + w)*32 + q*8 + lrow)*16 ; 16 bf16 = [nt0 r0..3][nt1][nt2][nt3]
__global__ __launch_bounds__(256, 1) void k1_xw(const float* __restrict__ x, const float* __restrict__ w1x,
                                               const float* __restrict__ b1x, const float* __restrict__ b1a,
                                               u16* __restrict__ xpre)
{
    const int t = blockIdx.x;
    const int tid = threadIdx.x, lane = tid & 63, w = tid >> 6;
    const int l15 = lane & 15, q = lane >> 4;
    const int cw = w * 64;

    bf16x8 bw[4][8];
    f32x4 biasv[4];
    #pragma unroll
    for (int nt = 0; nt < 4; ++nt){
        const int n0 = cw + nt * 16 + q * 4;
        f32x4 bx = *(const f32x4*)(b1x + n0);
        f32x4 ba = *(const f32x4*)(b1a + n0);
        biasv[nt] = (bx + ba) * C_TANH;
        const int n = cw + nt * 16 + l15;
        #pragma unroll
        for (int ks = 0; ks < 8; ++ks){
            u16x8 tt;
            #pragma unroll
            for (int j = 0; j < 8; ++j) tt[j] = f2b(w1x[(ks * 32 + q * 8 + j) * 256 + n] * C_TANH);
            bw[nt][ks] = __builtin_bit_cast(bf16x8, tt);
        }
    }

    for (int blk = 0; blk < 16; ++blk){
        const int b0r = blk * 16;
        bf16x8 av[8];
        #pragma unroll
        for (int ks = 0; ks < 8; ++ks){
            const float* p = x + ((size_t)(b0r + l15) * 512 + t) * 256 + ks * 32 + q * 8;
            f32x4 v0 = *(const f32x4*)p;
            f32x4 v1 = *(const f32x4*)(p + 4);
            u32x4 dd = { pkbf(v0[0], v0[1]), pkbf(v0[2], v0[3]),
                         pkbf(v1[0], v1[1]), pkbf(v1[2], v1[3]) };
            av[ks] = __builtin_bit_cast(bf16x8, dd);
        }
        f32x4 acc[4];
        #pragma unroll
        for (int nt = 0; nt < 4; ++nt) acc[nt] = biasv[nt];
        #pragma unroll
        for (int ks = 0; ks < 8; ++ks)
            #pragma unroll
            for (int nt = 0; nt < 4; ++nt)
                acc[nt] = MFMA16(bw[nt][ks], av[ks], acc[nt]);   // swapped: D[hidden][batch]
        const int bg = blk * 2 + (l15 >> 3);
        const size_t a16 = ((((size_t)t * 32 + bg) * 4 + w) * 32 + q * 8 + (l15 & 7)) * 16;
        u32x4 A  = { pkbf(acc[0][0], acc[0][1]), pkbf(acc[0][2], acc[0][3]),
                     pkbf(acc[1][0], acc[1][1]), pkbf(acc[1][2], acc[1][3]) };
        u32x4 Bv = { pkbf(acc[2][0], acc[2][1]), pkbf(acc[2][2], acc[2][3]),
                     pkbf(acc[3][0], acc[3][1]), pkbf(acc[3][2], acc[3][3]) };
        *(u32x4*)(xpre + a16)     = A;
        *(u32x4*)(xpre + a16 + 8) = Bv;
    }
}

// ---------------- K2: encoder, 32 wgs x 8 batch rows, dup-column B-frags, wide b64 writes ----------------
__global__ __launch_bounds__(256, 1) void k2_enc(const float* __restrict__ w1a, const u16* __restrict__ xpre,
                                                u16* __restrict__ alast)
{
    __shared__ __align__(16) u16 st[2][8][264];
    const int tid = threadIdx.x, lane = tid & 63, w = tid >> 6;
    const int l15 = lane & 15, q = lane >> 4;
    const int lrow = l15 & 7, hi = l15 >> 3;
    const bool lo8 = (hi == 0);
    const int bg = blockIdx.x;                     // 0..31, batches bg*8 .. bg*8+7

    bf16x8 bw[4][8];                               // C-scaled W1a as A-operand, full K, register-resident
    #pragma unroll
    for (int nt = 0; nt < 4; ++nt){
        const int n = w * 64 + nt * 16 + l15;
        #pragma unroll
        for (int ks = 0; ks < 8; ++ks){
            u16x8 tt;
            #pragma unroll
            for (int j = 0; j < 8; ++j) tt[j] = f2b(w1a[(ks * 32 + q * 8 + j) * 256 + n] * C_TANH);
            bw[nt][ks] = __builtin_bit_cast(bf16x8, tt);
        }
    }
    for (int i = tid; i < 8 * 264; i += 256) (&st[0][0][0])[i] = 0;   // a0 = 0 (st[1] fully written before read)
    __syncthreads();

    // lanes l15 and l15+8 load identical slots (dup) -> identical acc in both halves
    const u16* xp = xpre + ((((size_t)bg * 4 + w) * 32 + q * 8 + lrow) * 16);
    u32x4 c0 = *(const u32x4*)xp,           c1 = *(const u32x4*)(xp + 8);
    u32x4 a0 = *(const u32x4*)(xp + 65536), a1 = *(const u32x4*)(xp + 65536 + 8);

    const u16 (*sR)[264] = st[0];
    u16 (*sW)[264] = st[1];

    for (int t = 0; t < 512; ++t){
        const size_t tp = (size_t)((t + 2 < 512) ? t + 2 : 511) * 65536;
        u32x4 n0 = *(const u32x4*)(xp + tp);
        u32x4 n1 = *(const u32x4*)(xp + tp + 8);

        bf16x8 av[8];                              // B-operand: a[batch=lrow][k]; pair-lanes broadcast
        #pragma unroll
        for (int ks = 0; ks < 8; ++ks)
            av[ks] = *(const bf16x8*)&sR[lrow][ks * 32 + q * 8];

        f32x4 acc[4];                              // init = scaled xpre (saves the adds)
        #pragma unroll
        for (int nt = 0; nt < 4; ++nt){
            const u32x4 src = (nt < 2) ? c0 : c1;
            #pragma unroll
            for (int r = 0; r < 4; ++r){
                const u32 d = src[(nt & 1) * 2 + (r >> 1)];
                acc[nt][r] = ubit((r & 1) ? (d & 0xFFFF0000u) : (d << 16));
            }
        }
        #pragma unroll
        for (int ks = 0; ks < 8; ++ks)
            #pragma unroll
            for (int nt = 0; nt < 4; ++nt)
                acc[nt] = MFMA16(bw[nt][ks], av[ks], acc[nt]);   // swapped

        // dense tanh: lo half handles nt=p, hi half handles nt=p+2 (values duplicated across halves)
        #pragma unroll
        for (int p = 0; p < 2; ++p){
            float m[4];
            #pragma unroll
            for (int r = 0; r < 4; ++r){
                const float mv = lo8 ? acc[p][r] : acc[p + 2][r];
                const float e = __builtin_amdgcn_exp2f(mv);
                m[r] = 1.0f - 2.0f * __builtin_amdgcn_rcpf(e + 1.0f);
            }
            u32x2 hp = { pk_away(m[0], m[1]), pk_away(m[2], m[3]) };
            *(u32x2*)&sW[lrow][w * 64 + (p + 2 * hi) * 16 + q * 4] = hp;   // one b64 write
        }

        c0 = a0; c1 = a1; a0 = n0; a1 = n1;
        bar_lds();                                   // LDS-only drain; vmem stays in flight
        const u16 (*tmp)[264] = sR; sR = (const u16(*)[264])sW; sW = (u16(*)[264])tmp;
    }
    {
        const int row = tid >> 5, c8 = (tid & 31) * 8;
        *(u32x4*)(alast + (size_t)(bg * 8 + row) * 256 + c8) = *(const u32x4*)&sR[row][c8];
    }
}

// ---------------- K3pre: y0 = sigmoid(alast@Wy+by); inj = C*(y0@W2x) in k3a slot order ----------------
__global__ __launch_bounds__(256, 1) void k3_pre(const float* __restrict__ wy, const float* __restrict__ by,
                                                const float* __restrict__ w2x,
                                                const u16* __restrict__ alast, float* __restrict__ injws)
{
    __shared__ __align__(16) u16 st[16][264];
    __shared__ __align__(16) u16 y0s[16][264];
    const int tid = threadIdx.x, lane = tid & 63, w = tid >> 6;
    const int l15 = lane & 15, q = lane >> 4;
    const int lrow = l15 & 7, hi = l15 >> 3;
    const int bg = blockIdx.x;                     // 0..15, batches bg*16 .. bg*16+15
    {
        const int row = tid >> 4, c = (tid & 15) * 16;
        #pragma unroll
        for (int j = 0; j < 2; ++j)
            *(u32x4*)&st[row][c + j * 8] = *(const u32x4*)(alast + (size_t)(bg * 16 + row) * 256 + c + j * 8);
    }
    __syncthreads();
    {   // y0 = sigm(alast@Wy+by), Wy scaled by -log2e; swapped -> wide b64 y0s writes
        bf16x8 bwy[4][8];
        f32x4 biasy[4];
        #pragma unroll
        for (int nt = 0; nt < 4; ++nt){
            const int n0 = w * 64 + nt * 16 + q * 4;
            biasy[nt] = (*(const f32x4*)(by + n0)) * NL2E;
            const int n = w * 64 + nt * 16 + l15;
            #pragma unroll
            for (int ks = 0; ks < 8; ++ks){
                u16x8 tt;
                #pragma unroll
                for (int j = 0; j < 8; ++j) tt[j] = f2b(wy[(ks * 32 + q * 8 + j) * 256 + n] * NL2E);
                bwy[nt][ks] = __builtin_bit_cast(bf16x8, tt);
            }
        }
        bf16x8 av[8];
        #pragma unroll
        for (int ks = 0; ks < 8; ++ks) av[ks] = *(const bf16x8*)&st[l15][ks * 32 + q * 8];
        f32x4 acc[4];
        #pragma unroll
        for (int nt = 0; nt < 4; ++nt) acc[nt] = biasy[nt];
        #pragma unroll
        for (int ks = 0; ks < 8; ++ks)
            #pragma unroll
            for (int nt = 0; nt < 4; ++nt) acc[nt] = MFMA16(bwy[nt][ks], av[ks], acc[nt]);
        #pragma unroll
        for (int nt = 0; nt < 4; ++nt){
            float y[4];
            #pragma unroll
            for (int r = 0; r < 4; ++r) y[r] = __builtin_amdgcn_rcpf(1.0f + __builtin_amdgcn_exp2f(acc[nt][r]));
            u32x2 hp = { pkbf(y[0], y[1]), pkbf(y[2], y[3]) };
            *(u32x2*)&y0s[l15][w * 64 + nt * 16 + q * 4] = hp;
        }
    }
    __syncthreads();
    {   // inj = C * (y0 @ W2x)  (no bias), stored in k3a's per-lane slot order
        bf16x8 av[8];
        #pragma unroll
        for (int ks = 0; ks < 8; ++ks) av[ks] = *(const bf16x8*)&y0s[l15][ks * 32 + q * 8];
        f32x4 acc[4];
        #pragma unroll
        for (int nt = 0; nt < 4; ++nt) acc[nt] = (f32x4){0.f, 0.f, 0.f, 0.f};
        #pragma unroll
        for (int ks = 0; ks < 8; ++ks)
            #pragma unroll
            for (int nt = 0; nt < 4; ++nt){
                const int n = w * 64 + nt * 16 + l15;
                u16x8 tt;
                #pragma unroll
                for (int j = 0; j < 8; ++j) tt[j] = f2b(w2x[(ks * 32 + q * 8 + j) * 256 + n] * C_TANH);
                acc[nt] = MFMA16(__builtin_bit_cast(bf16x8, tt), av[ks], acc[nt]);
            }
        // slot for k3a wg bg32 = bg*2 + hi (batch = bg32*8 + lrow = bg*16 + l15)
        const size_t ib = ((((size_t)(bg * 2 + hi)) * 4 + w) * 32 + q * 8 + lrow) * 16;
        #pragma unroll
        for (int nt = 0; nt < 4; ++nt)
            *(f32x4*)(injws + ib + nt * 4) = acc[nt];
    }
}

// ---------------- K3a: decoder recurrence, 32 wgs x 8 rows, stores all 64 states wide ----------------
__global__ __launch_bounds__(256, 1) void k3_rec(const float* __restrict__ w2a, const float* __restrict__ b2x,
                                                const float* __restrict__ b2a, const u16* __restrict__ alast,
                                                const float* __restrict__ injws, u16* __restrict__ astate)
{
    __shared__ __align__(16) u16 st[2][8][264];
    const int tid = threadIdx.x, lane = tid & 63, w = tid >> 6;
    const int l15 = lane & 15, q = lane >> 4;
    const int lrow = l15 & 7, hi = l15 >> 3;
    const bool lo8 = (hi == 0);
    const int bg = blockIdx.x;                     // 0..31

    bf16x8 bw[4][8];
    f32x4 bias2[4];
    #pragma unroll
    for (int nt = 0; nt < 4; ++nt){
        const int n0 = w * 64 + nt * 16 + q * 4;
        f32x4 bx = *(const f32x4*)(b2x + n0);
        f32x4 ba = *(const f32x4*)(b2a + n0);
        bias2[nt] = (bx + ba) * C_TANH;
        const int n = w * 64 + nt * 16 + l15;
        #pragma unroll
        for (int ks = 0; ks < 8; ++ks){
            u16x8 tt;
            #pragma unroll
            for (int j = 0; j < 8; ++j) tt[j] = f2b(w2a[(ks * 32 + q * 8 + j) * 256 + n] * C_TANH);
            bw[nt][ks] = __builtin_bit_cast(bf16x8, tt);
        }
    }
    f32x4 ini[4];
    {
        const size_t ib = (((size_t)bg * 4 + w) * 32 + q * 8 + lrow) * 16;   // dup across hi
        #pragma unroll
        for (int nt = 0; nt < 4; ++nt)
            ini[nt] = *(const f32x4*)(injws + ib + nt * 4) + bias2[nt];      // i==0 init; reset after first step
    }
    {
        const int row = tid >> 5, c8 = (tid & 31) * 8;
        *(u32x4*)&st[0][row][c8] = *(const u32x4*)(alast + (size_t)(bg * 8 + row) * 256 + c8);
    }
    __syncthreads();

    const u16 (*sR)[264] = st[0];
    u16 (*sW)[264] = st[1];

    for (int i = 0; i < 64; ++i){
        bf16x8 av[8];
        #pragma unroll
        for (int ks = 0; ks < 8; ++ks) av[ks] = *(const bf16x8*)&sR[lrow][ks * 32 + q * 8];
        f32x4 acc[4];
        #pragma unroll
        for (int nt = 0; nt < 4; ++nt) acc[nt] = ini[nt];
        #pragma unroll
        for (int ks = 0; ks < 8; ++ks)
            #pragma unroll
            for (int nt = 0; nt < 4; ++nt) acc[nt] = MFMA16(bw[nt][ks], av[ks], acc[nt]);

        #pragma unroll
        for (int p = 0; p < 2; ++p){
            float m[4];
            #pragma unroll
            for (int r = 0; r < 4; ++r){
                const float mv = lo8 ? acc[p][r] : acc[p + 2][r];
                const float e = __builtin_amdgcn_exp2f(mv);
                m[r] = 1.0f - 2.0f * __builtin_amdgcn_rcpf(e + 1.0f);
            }
            u32x2 hp = { pk_away(m[0], m[1]), pk_away(m[2], m[3]) };
            *(u32x2*)&sW[lrow][w * 64 + (p + 2 * hi) * 16 + q * 4] = hp;
            *(u32x2*)(astate + ((size_t)i * 256 + bg * 8 + lrow) * 256
                              + w * 64 + (p + 2 * hi) * 16 + q * 4) = hp;   // async vmem, not drained by bar_lds
        }
        if (i == 0){
            #pragma unroll
            for (int nt = 0; nt < 4; ++nt) ini[nt] = bias2[nt];
        }
        bar_lds();
        const u16 (*tmp)[264] = sR; sR = (const u16(*)[264])sW; sW = (u16(*)[264])tmp;
    }
}

// ---------------- K3b: out = sigm(astate@Wy + by), wide f32x4 stores ----------------
__global__ __launch_bounds__(256, 1) void k3_out(const float* __restrict__ wy, const float* __restrict__ by,
                                                const u16* __restrict__ astate, float* __restrict__ out)
{
    const int tid = threadIdx.x, lane = tid & 63, w = tid >> 6;
    const int l15 = lane & 15, q = lane >> 4;

    bf16x8 bwy[4][8];
    f32x4 biasy[4];
    #pragma unroll
    for (int nt = 0; nt < 4; ++nt){
        const int n0 = w * 64 + nt * 16 + q * 4;
        biasy[nt] = (*(const f32x4*)(by + n0)) * NL2E;
        const int n = w * 64 + nt * 16 + l15;
        #pragma unroll
        for (int ks = 0; ks < 8; ++ks){
            u16x8 tt;
            #pragma unroll
            for (int j = 0; j < 8; ++j) tt[j] = f2b(wy[(ks * 32 + q * 8 + j) * 256 + n] * NL2E);
            bwy[nt][ks] = __builtin_bit_cast(bf16x8, tt);
        }
    }
    #pragma unroll
    for (int tix = 0; tix < 4; ++tix){
        const int R0 = (blockIdx.x * 4 + tix) * 16;          // flat row = i*256 + b
        bf16x8 av[8];
        #pragma unroll
        for (int ks = 0; ks < 8; ++ks)
            av[ks] = *(const bf16x8*)(astate + (size_t)(R0 + l15) * 256 + ks * 32 + q * 8);
        f32x4 acc[4];
        #pragma unroll
        for (int nt = 0; nt < 4; ++nt) acc[nt] = biasy[nt];
        #pragma unroll
        for (int ks = 0; ks < 8; ++ks)
            #pragma unroll
            for (int nt = 0; nt < 4; ++nt) acc[nt] = MFMA16(bwy[nt][ks], av[ks], acc[nt]);
        const int R = R0 + l15, ii = R >> 8, b = R & 255;
        #pragma unroll
        for (int nt = 0; nt < 4; ++nt){
            f32x4 o4;
            #pragma unroll
            for (int r = 0; r < 4; ++r)
                o4[r] = __builtin_amdgcn_rcpf(1.0f + __builtin_amdgcn_exp2f(acc[nt][r]));
            *(f32x4*)(out + ((size_t)b * 64 + ii) * 256 + w * 64 + nt * 16 + q * 4) = o4;
        }
    }
}

extern "C" void kernel_launch(void* const* d_in, const int* in_sizes, int n_in,
                              void* d_out, int out_size, void* d_ws, size_t ws_size,
                              hipStream_t stream) {
    const float* x   = (const float*)d_in[0];
    const float* w1x = (const float*)d_in[1];
    const float* b1x = (const float*)d_in[2];
    const float* w1a = (const float*)d_in[3];
    const float* b1a = (const float*)d_in[4];
    const float* w2x = (const float*)d_in[5];
    const float* b2x = (const float*)d_in[6];
    const float* w2a = (const float*)d_in[7];
    const float* b2a = (const float*)d_in[8];
    const float* wy  = (const float*)d_in[9];
    const float* by  = (const float*)d_in[10];

    u16*   xpre   = (u16*)d_ws;                     // 64 MiB (k1->k2), then reused:
    u16*   astate = (u16*)d_ws;                     // 8 MiB (k3a->k3b), aliases xpre (k2 done)
    u16*   alast  = xpre + (size_t)512 * 16 * 512 * 8;
    float* injws  = (float*)(alast + 256 * 256);    // 64K f32
    float* o      = (float*)d_out;

    k1_xw <<<512, 256, 0, stream>>>(x, w1x, b1x, b1a, xpre);
    k2_enc<<<32,  256, 0, stream>>>(w1a, xpre, alast);
    k3_pre<<<16,  256, 0, stream>>>(wy, by, w2x, alast, injws);
    k3_rec<<<32,  256, 0, stream>>>(w2a, b2x, b2a, alast, injws, astate);
    k3_out<<<256, 256, 0, stream>>>(wy, by, astate, o);
}

// Round 2
// 585.369 us; speedup vs baseline: 1.4164x; 1.1373x over previous
//
#include <hip/hip_runtime.h>

// B=256, S=512, I=H=O=256, L=64. fp32 in/out; bf16 MFMA internally.
// Operand-swapped MFMA everywhere: D = mfma(W_frag, a_frag) = D[hidden][batch].
// k2/k3a: 32 wgs x 8 batch rows, EIGHT waves (2 per SIMD) x 32 hidden cols each.
//   2 waves/SIMD lets wave A's MFMA overlap wave B's tanh VALU chain (1-wave/SIMD
//   serialized them: step was ~620cy MFMA + ~310cy VALU back-to-back).
// Column-duplicated B-frags (lanes l15/l15+8 broadcast-read same LDS slot) ->
//   acc duplicated across lane halves -> each lane tanh's only 4 real values.
typedef unsigned short u16;
typedef unsigned int   u32;
typedef __attribute__((ext_vector_type(8))) __bf16 bf16x8;
typedef __attribute__((ext_vector_type(8))) u16    u16x8;
typedef __attribute__((ext_vector_type(4))) float  f32x4;
typedef __attribute__((ext_vector_type(4))) u32    u32x4;
typedef __attribute__((ext_vector_type(2))) u32    u32x2;

#define MFMA16(a,b,c) __builtin_amdgcn_mfma_f32_16x16x32_bf16((a),(b),(c),0,0,0)
#define C_TANH 2.8853900817779268f   /* 2*log2(e): tanh(v)=1-2/(2^(C*v)+1) */
#define NL2E  -1.4426950408889634f   /* -log2(e): sigm(u)=1/(1+2^(NL2E*u)) */

__device__ __forceinline__ float ubit(u32 x){ return __builtin_bit_cast(float, x); }
__device__ __forceinline__ u16 f2b(float f){ // RNE f32->bf16 (prep paths)
    u32 b = __builtin_bit_cast(u32, f);
    b += 0x7FFFu + ((b >> 16) & 1u);
    return (u16)(b >> 16);
}
__device__ __forceinline__ u32 pkbf(float a, float b){ return ((u32)f2b(b) << 16) | (u32)f2b(a); }
__device__ __forceinline__ u32 pk_away(float a, float b){ // round-away pack (state path)
    u32 ua = (__builtin_bit_cast(u32, a) + 0x8000u) >> 16;
    u32 ub = (__builtin_bit_cast(u32, b) + 0x8000u) & 0xFFFF0000u;
    return ub | ua;
}
// Barrier that drains ONLY LDS counters -- vmem (prefetch/stores) stays in flight.
__device__ __forceinline__ void bar_lds(){ __asm__ volatile("s_waitcnt lgkmcnt(0)\n\ts_barrier" ::: "memory"); }

// ---------------- K1: xpre = C*(x@W1x + b1x + b1a), in k2's 8-wave slot order ----------------
// slot (8 u16 = [nt0 r0..3][nt1 r0..3]) at u16 addr ((((t*32+bg)*8 + w8)*32 + q*8 + lrow)*8;
// holds hidden cols w8*32 + nt*16 + q*4 + r for batch bg*8+lrow.
__global__ __launch_bounds__(256, 1) void k1_xw(const float* __restrict__ x, const float* __restrict__ w1x,
                                               const float* __restrict__ b1x, const float* __restrict__ b1a,
                                               u16* __restrict__ xpre)
{
    const int t = blockIdx.x;
    const int tid = threadIdx.x, lane = tid & 63, w = tid >> 6;
    const int l15 = lane & 15, q = lane >> 4;
    const int lrow = l15 & 7, hi = l15 >> 3;
    const int cw = w * 64;

    bf16x8 bw[4][8];
    f32x4 biasv[4];
    #pragma unroll
    for (int nt = 0; nt < 4; ++nt){
        const int n0 = cw + nt * 16 + q * 4;
        f32x4 bx = *(const f32x4*)(b1x + n0);
        f32x4 ba = *(const f32x4*)(b1a + n0);
        biasv[nt] = (bx + ba) * C_TANH;
        const int n = cw + nt * 16 + l15;
        #pragma unroll
        for (int ks = 0; ks < 8; ++ks){
            u16x8 tt;
            #pragma unroll
            for (int j = 0; j < 8; ++j) tt[j] = f2b(w1x[(ks * 32 + q * 8 + j) * 256 + n] * C_TANH);
            bw[nt][ks] = __builtin_bit_cast(bf16x8, tt);
        }
    }

    for (int blk = 0; blk < 16; ++blk){
        const int b0r = blk * 16;
        bf16x8 av[8];
        #pragma unroll
        for (int ks = 0; ks < 8; ++ks){
            const float* p = x + ((size_t)(b0r + l15) * 512 + t) * 256 + ks * 32 + q * 8;
            f32x4 v0 = *(const f32x4*)p;
            f32x4 v1 = *(const f32x4*)(p + 4);
            u32x4 dd = { pkbf(v0[0], v0[1]), pkbf(v0[2], v0[3]),
                         pkbf(v1[0], v1[1]), pkbf(v1[2], v1[3]) };
            av[ks] = __builtin_bit_cast(bf16x8, dd);
        }
        f32x4 acc[4];
        #pragma unroll
        for (int nt = 0; nt < 4; ++nt) acc[nt] = biasv[nt];
        #pragma unroll
        for (int ks = 0; ks < 8; ++ks)
            #pragma unroll
            for (int nt = 0; nt < 4; ++nt)
                acc[nt] = MFMA16(bw[nt][ks], av[ks], acc[nt]);   // swapped: D[hidden][batch]
        const int bg = blk * 2 + hi;
        #pragma unroll
        for (int p2 = 0; p2 < 2; ++p2){
            const int w8 = w * 2 + p2;
            const size_t a16 = ((((size_t)t * 32 + bg) * 8 + w8) * 32 + q * 8 + lrow) * 8;
            u32x4 V = { pkbf(acc[p2 * 2][0], acc[p2 * 2][1]), pkbf(acc[p2 * 2][2], acc[p2 * 2][3]),
                        pkbf(acc[p2 * 2 + 1][0], acc[p2 * 2 + 1][1]), pkbf(acc[p2 * 2 + 1][2], acc[p2 * 2 + 1][3]) };
            *(u32x4*)(xpre + a16) = V;
        }
    }
}

// ---------------- K2: encoder, 32 wgs x 512 thr (8 waves, 2/SIMD), dup-column B-frags ----------------
__global__ __launch_bounds__(512, 2) void k2_enc(const float* __restrict__ w1a, const u16* __restrict__ xpre,
                                                u16* __restrict__ alast)
{
    __shared__ __align__(16) u16 st[2][8][264];
    const int tid = threadIdx.x, lane = tid & 63, w = tid >> 6;   // w 0..7, 32 hidden cols each
    const int l15 = lane & 15, q = lane >> 4;
    const int lrow = l15 & 7, hi = l15 >> 3;
    const int bg = blockIdx.x;                     // 0..31, batches bg*8 .. bg*8+7

    bf16x8 bw[2][8];                               // C-scaled W1a as A-operand (32 cols), reg-resident
    #pragma unroll
    for (int nt = 0; nt < 2; ++nt){
        const int n = w * 32 + nt * 16 + l15;
        #pragma unroll
        for (int ks = 0; ks < 8; ++ks){
            u16x8 tt;
            #pragma unroll
            for (int j = 0; j < 8; ++j) tt[j] = f2b(w1a[(ks * 32 + q * 8 + j) * 256 + n] * C_TANH);
            bw[nt][ks] = __builtin_bit_cast(bf16x8, tt);
        }
    }
    for (int i = tid; i < 8 * 264; i += 512) (&st[0][0][0])[i] = 0;   // a0 = 0
    __syncthreads();

    // per-lane xpre slot: 8 bf16 = one dwordx4 per step (dup across hi)
    const u16* xp = xpre + ((((size_t)bg) * 8 + w) * 32 + q * 8 + lrow) * 8;
    u32x4 c = *(const u32x4*)xp;
    u32x4 a = *(const u32x4*)(xp + 65536);

    const u16 (*sR)[264] = st[0];
    u16 (*sW)[264] = st[1];

    for (int t = 0; t < 512; ++t){
        const size_t tp = (size_t)((t + 2 < 512) ? t + 2 : 511) * 65536;
        u32x4 n_ = *(const u32x4*)(xp + tp);

        bf16x8 av[8];                              // B-operand: a[batch=lrow][k]; hi lanes broadcast
        #pragma unroll
        for (int ks = 0; ks < 8; ++ks)
            av[ks] = *(const bf16x8*)&sR[lrow][ks * 32 + q * 8];

        f32x4 acc[2];                              // init = scaled xpre
        #pragma unroll
        for (int nt = 0; nt < 2; ++nt)
            #pragma unroll
            for (int r = 0; r < 4; ++r){
                const u32 d = c[nt * 2 + (r >> 1)];
                acc[nt][r] = ubit((r & 1) ? (d & 0xFFFF0000u) : (d << 16));
            }
        #pragma unroll
        for (int ks = 0; ks < 8; ++ks)
            #pragma unroll
            for (int nt = 0; nt < 2; ++nt)
                acc[nt] = MFMA16(bw[nt][ks], av[ks], acc[nt]);   // swapped

        // dense tanh: lo half handles nt=0, hi half nt=1 (values duplicated across halves)
        float m[4];
        #pragma unroll
        for (int r = 0; r < 4; ++r){
            const float mv = hi ? acc[1][r] : acc[0][r];
            const float e = __builtin_amdgcn_exp2f(mv);
            m[r] = 1.0f - 2.0f * __builtin_amdgcn_rcpf(e + 1.0f);
        }
        u32x2 hp = { pk_away(m[0], m[1]), pk_away(m[2], m[3]) };
        *(u32x2*)&sW[lrow][w * 32 + hi * 16 + q * 4] = hp;       // one b64 write

        c = a; a = n_;
        bar_lds();                                   // LDS-only drain; vmem stays in flight
        const u16 (*tmp)[264] = sR; sR = (const u16(*)[264])sW; sW = (u16(*)[264])tmp;
    }
    if (tid < 256){
        const int row = tid >> 5, c8 = (tid & 31) * 8;
        *(u32x4*)(alast + (size_t)(bg * 8 + row) * 256 + c8) = *(const u32x4*)&sR[row][c8];
    }
}

// ---------------- K3pre: y0 = sigmoid(alast@Wy+by); inj = C*(y0@W2x) in k3a slot order ----------------
__global__ __launch_bounds__(256, 1) void k3_pre(const float* __restrict__ wy, const float* __restrict__ by,
                                                const float* __restrict__ w2x,
                                                const u16* __restrict__ alast, float* __restrict__ injws)
{
    __shared__ __align__(16) u16 st[16][264];
    __shared__ __align__(16) u16 y0s[16][264];
    const int tid = threadIdx.x, lane = tid & 63, w = tid >> 6;
    const int l15 = lane & 15, q = lane >> 4;
    const int lrow = l15 & 7, hi = l15 >> 3;
    const int bg = blockIdx.x;                     // 0..15, batches bg*16 .. bg*16+15
    {
        const int row = tid >> 4, c = (tid & 15) * 16;
        #pragma unroll
        for (int j = 0; j < 2; ++j)
            *(u32x4*)&st[row][c + j * 8] = *(const u32x4*)(alast + (size_t)(bg * 16 + row) * 256 + c + j * 8);
    }
    __syncthreads();
    {   // y0 = sigm(alast@Wy+by), Wy scaled by -log2e; swapped -> wide b64 y0s writes
        bf16x8 bwy[4][8];
        f32x4 biasy[4];
        #pragma unroll
        for (int nt = 0; nt < 4; ++nt){
            const int n0 = w * 64 + nt * 16 + q * 4;
            biasy[nt] = (*(const f32x4*)(by + n0)) * NL2E;
            const int n = w * 64 + nt * 16 + l15;
            #pragma unroll
            for (int ks = 0; ks < 8; ++ks){
                u16x8 tt;
                #pragma unroll
                for (int j = 0; j < 8; ++j) tt[j] = f2b(wy[(ks * 32 + q * 8 + j) * 256 + n] * NL2E);
                bwy[nt][ks] = __builtin_bit_cast(bf16x8, tt);
            }
        }
        bf16x8 av[8];
        #pragma unroll
        for (int ks = 0; ks < 8; ++ks) av[ks] = *(const bf16x8*)&st[l15][ks * 32 + q * 8];
        f32x4 acc[4];
        #pragma unroll
        for (int nt = 0; nt < 4; ++nt) acc[nt] = biasy[nt];
        #pragma unroll
        for (int ks = 0; ks < 8; ++ks)
            #pragma unroll
            for (int nt = 0; nt < 4; ++nt) acc[nt] = MFMA16(bwy[nt][ks], av[ks], acc[nt]);
        #pragma unroll
        for (int nt = 0; nt < 4; ++nt){
            float y[4];
            #pragma unroll
            for (int r = 0; r < 4; ++r) y[r] = __builtin_amdgcn_rcpf(1.0f + __builtin_amdgcn_exp2f(acc[nt][r]));
            u32x2 hp = { pkbf(y[0], y[1]), pkbf(y[2], y[3]) };
            *(u32x2*)&y0s[l15][w * 64 + nt * 16 + q * 4] = hp;
        }
    }
    __syncthreads();
    {   // inj = C * (y0 @ W2x)  (no bias), stored in k3a's 8-wave per-lane slot order
        bf16x8 av[8];
        #pragma unroll
        for (int ks = 0; ks < 8; ++ks) av[ks] = *(const bf16x8*)&y0s[l15][ks * 32 + q * 8];
        f32x4 acc[4];
        #pragma unroll
        for (int nt = 0; nt < 4; ++nt) acc[nt] = (f32x4){0.f, 0.f, 0.f, 0.f};
        #pragma unroll
        for (int ks = 0; ks < 8; ++ks)
            #pragma unroll
            for (int nt = 0; nt < 4; ++nt){
                const int n = w * 64 + nt * 16 + l15;
                u16x8 tt;
                #pragma unroll
                for (int j = 0; j < 8; ++j) tt[j] = f2b(w2x[(ks * 32 + q * 8 + j) * 256 + n] * C_TANH);
                acc[nt] = MFMA16(__builtin_bit_cast(bf16x8, tt), av[ks], acc[nt]);
            }
        // k3a wg = bg*2+hi (batch = bg*16+l15), wave w8 = w*2+(nt>>1), nt_local = nt&1
        #pragma unroll
        for (int nt = 0; nt < 4; ++nt){
            const size_t ib = ((((size_t)(bg * 2 + hi)) * 8 + (size_t)(w * 2 + (nt >> 1))) * 32
                               + q * 8 + lrow) * 8 + (nt & 1) * 4;
            *(f32x4*)(injws + ib) = acc[nt];
        }
    }
}

// ---------------- K3a: decoder recurrence, 32 wgs x 512 thr (8 waves, 2/SIMD) ----------------
__global__ __launch_bounds__(512, 2) void k3_rec(const float* __restrict__ w2a, const float* __restrict__ b2x,
                                                const float* __restrict__ b2a, const u16* __restrict__ alast,
                                                const float* __restrict__ injws, u16* __restrict__ astate)
{
    __shared__ __align__(16) u16 st[2][8][264];
    const int tid = threadIdx.x, lane = tid & 63, w = tid >> 6;   // w 0..7
    const int l15 = lane & 15, q = lane >> 4;
    const int lrow = l15 & 7, hi = l15 >> 3;
    const int bg = blockIdx.x;                     // 0..31

    bf16x8 bw[2][8];
    f32x4 bias2[2];
    #pragma unroll
    for (int nt = 0; nt < 2; ++nt){
        const int n0 = w * 32 + nt * 16 + q * 4;
        f32x4 bx = *(const f32x4*)(b2x + n0);
        f32x4 ba = *(const f32x4*)(b2a + n0);
        bias2[nt] = (bx + ba) * C_TANH;
        const int n = w * 32 + nt * 16 + l15;
        #pragma unroll
        for (int ks = 0; ks < 8; ++ks){
            u16x8 tt;
            #pragma unroll
            for (int j = 0; j < 8; ++j) tt[j] = f2b(w2a[(ks * 32 + q * 8 + j) * 256 + n] * C_TANH);
            bw[nt][ks] = __builtin_bit_cast(bf16x8, tt);
        }
    }
    f32x4 ini[2];
    {
        const size_t ib = (((size_t)bg * 8 + w) * 32 + q * 8 + lrow) * 8;   // dup across hi
        #pragma unroll
        for (int nt = 0; nt < 2; ++nt)
            ini[nt] = *(const f32x4*)(injws + ib + nt * 4) + bias2[nt];     // i==0 init; reset after
    }
    if (tid < 256){
        const int row = tid >> 5, c8 = (tid & 31) * 8;
        *(u32x4*)&st[0][row][c8] = *(const u32x4*)(alast + (size_t)(bg * 8 + row) * 256 + c8);
    }
    __syncthreads();

    const u16 (*sR)[264] = st[0];
    u16 (*sW)[264] = st[1];

    for (int i = 0; i < 64; ++i){
        bf16x8 av[8];
        #pragma unroll
        for (int ks = 0; ks < 8; ++ks) av[ks] = *(const bf16x8*)&sR[lrow][ks * 32 + q * 8];
        f32x4 acc[2];
        #pragma unroll
        for (int nt = 0; nt < 2; ++nt) acc[nt] = ini[nt];
        #pragma unroll
        for (int ks = 0; ks < 8; ++ks)
            #pragma unroll
            for (int nt = 0; nt < 2; ++nt) acc[nt] = MFMA16(bw[nt][ks], av[ks], acc[nt]);

        float m[4];
        #pragma unroll
        for (int r = 0; r < 4; ++r){
            const float mv = hi ? acc[1][r] : acc[0][r];
            const float e = __builtin_amdgcn_exp2f(mv);
            m[r] = 1.0f - 2.0f * __builtin_amdgcn_rcpf(e + 1.0f);
        }
        u32x2 hp = { pk_away(m[0], m[1]), pk_away(m[2], m[3]) };
        *(u32x2*)&sW[lrow][w * 32 + hi * 16 + q * 4] = hp;
        *(u32x2*)(astate + ((size_t)i * 256 + bg * 8 + lrow) * 256
                          + w * 32 + hi * 16 + q * 4) = hp;       // async vmem, not drained by bar_lds

        if (i == 0){
            #pragma unroll
            for (int nt = 0; nt < 2; ++nt) ini[nt] = bias2[nt];
        }
        bar_lds();
        const u16 (*tmp)[264] = sR; sR = (const u16(*)[264])sW; sW = (u16(*)[264])tmp;
    }
}

// ---------------- K3b: out = sigm(astate@Wy + by), wide f32x4 stores ----------------
__global__ __launch_bounds__(256, 1) void k3_out(const float* __restrict__ wy, const float* __restrict__ by,
                                                const u16* __restrict__ astate, float* __restrict__ out)
{
    const int tid = threadIdx.x, lane = tid & 63, w = tid >> 6;
    const int l15 = lane & 15, q = lane >> 4;

    bf16x8 bwy[4][8];
    f32x4 biasy[4];
    #pragma unroll
    for (int nt = 0; nt < 4; ++nt){
        const int n0 = w * 64 + nt * 16 + q * 4;
        biasy[nt] = (*(const f32x4*)(by + n0)) * NL2E;
        const int n = w * 64 + nt * 16 + l15;
        #pragma unroll
        for (int ks = 0; ks < 8; ++ks){
            u16x8 tt;
            #pragma unroll
            for (int j = 0; j < 8; ++j) tt[j] = f2b(wy[(ks * 32 + q * 8 + j) * 256 + n] * NL2E);
            bwy[nt][ks] = __builtin_bit_cast(bf16x8, tt);
        }
    }
    #pragma unroll
    for (int tix = 0; tix < 4; ++tix){
        const int R0 = (blockIdx.x * 4 + tix) * 16;          // flat row = i*256 + b
        bf16x8 av[8];
        #pragma unroll
        for (int ks = 0; ks < 8; ++ks)
            av[ks] = *(const bf16x8*)(astate + (size_t)(R0 + l15) * 256 + ks * 32 + q * 8);
        f32x4 acc[4];
        #pragma unroll
        for (int nt = 0; nt < 4; ++nt) acc[nt] = biasy[nt];
        #pragma unroll
        for (int ks = 0; ks < 8; ++ks)
            #pragma unroll
            for (int nt = 0; nt < 4; ++nt) acc[nt] = MFMA16(bwy[nt][ks], av[ks], acc[nt]);
        const int R = R0 + l15, ii = R >> 8, b = R & 255;
        #pragma unroll
        for (int nt = 0; nt < 4; ++nt){
            f32x4 o4;
            #pragma unroll
            for (int r = 0; r < 4; ++r)
                o4[r] = __builtin_amdgcn_rcpf(1.0f + __builtin_amdgcn_exp2f(acc[nt][r]));
            *(f32x4*)(out + ((size_t)b * 64 + ii) * 256 + w * 64 + nt * 16 + q * 4) = o4;
        }
    }
}

extern "C" void kernel_launch(void* const* d_in, const int* in_sizes, int n_in,
                              void* d_out, int out_size, void* d_ws, size_t ws_size,
                              hipStream_t stream) {
    const float* x   = (const float*)d_in[0];
    const float* w1x = (const float*)d_in[1];
    const float* b1x = (const float*)d_in[2];
    const float* w1a = (const float*)d_in[3];
    const float* b1a = (const float*)d_in[4];
    const float* w2x = (const float*)d_in[5];
    const float* b2x = (const float*)d_in[6];
    const float* w2a = (const float*)d_in[7];
    const float* b2a = (const float*)d_in[8];
    const float* wy  = (const float*)d_in[9];
    const float* by  = (const float*)d_in[10];

    u16*   xpre   = (u16*)d_ws;                     // 64 MiB (k1->k2), then reused:
    u16*   astate = (u16*)d_ws;                     // 8 MiB (k3a->k3b), aliases xpre (k2 done)
    u16*   alast  = xpre + (size_t)512 * 16 * 512 * 8;
    float* injws  = (float*)(alast + 256 * 256);    // 64K f32
    float* o      = (float*)d_out;

    k1_xw <<<512, 256, 0, stream>>>(x, w1x, b1x, b1a, xpre);
    k2_enc<<<32,  512, 0, stream>>>(w1a, xpre, alast);
    k3_pre<<<16,  256, 0, stream>>>(wy, by, w2x, alast, injws);
    k3_rec<<<32,  512, 0, stream>>>(w2a, b2x, b2a, alast, injws, astate);
    k3_out<<<256, 256, 0, stream>>>(wy, by, astate, o);
}

// Round 4
// 555.099 us; speedup vs baseline: 1.4937x; 1.0545x over previous
//
#include <hip/hip_runtime.h>

// B=256, S=512, I=H=O=256, L=64. fp32 in/out; bf16 MFMA internally.
// Operand-swapped MFMA everywhere: D = mfma(W_frag, a_frag) = D[hidden][batch].
// k2/k3a: 64 wgs x 4 batch rows (dup-4), 8 waves (2/SIMD) x 32 hidden cols each.
//   MFMA B-operand columns are 4x duplicated (lanes l15, l15+4, l15+8, l15+12
//   broadcast-read the same LDS slot) -> acc quadruplicated across lane groups ->
//   each lane tanh's only TWO real values (nt = bit2 of l15, r-pair = bit3):
//   trans 256->128 cy/SIMD/step, ds_read distinct bytes 512->256 (2 clk).
// LDS row stride 272 u16 (136 dw = 8 mod 32): reads 2-per-bank-quad even, writes 2-way.
typedef unsigned short u16;
typedef unsigned int   u32;
typedef __attribute__((ext_vector_type(8))) __bf16 bf16x8;
typedef __attribute__((ext_vector_type(8))) u16    u16x8;
typedef __attribute__((ext_vector_type(4))) float  f32x4;
typedef __attribute__((ext_vector_type(4))) u32    u32x4;
typedef __attribute__((ext_vector_type(2))) u32    u32x2;

#define MFMA16(a,b,c) __builtin_amdgcn_mfma_f32_16x16x32_bf16((a),(b),(c),0,0,0)
#define C_TANH 2.8853900817779268f   /* 2*log2(e): tanh(v)=1-2/(2^(C*v)+1) */
#define NL2E  -1.4426950408889634f   /* -log2(e): sigm(u)=1/(1+2^(NL2E*u)) */

__device__ __forceinline__ float ubit(u32 x){ return __builtin_bit_cast(float, x); }
__device__ __forceinline__ u16 f2b(float f){ // RNE f32->bf16 (prep paths)
    u32 b = __builtin_bit_cast(u32, f);
    b += 0x7FFFu + ((b >> 16) & 1u);
    return (u16)(b >> 16);
}
__device__ __forceinline__ u32 pkbf(float a, float b){ return ((u32)f2b(b) << 16) | (u32)f2b(a); }
__device__ __forceinline__ u32 pk_away(float a, float b){ // round-away pack (state path)
    u32 ua = (__builtin_bit_cast(u32, a) + 0x8000u) >> 16;
    u32 ub = (__builtin_bit_cast(u32, b) + 0x8000u) & 0xFFFF0000u;
    return ub | ua;
}
// Barrier that drains ONLY LDS counters -- vmem (prefetch/stores) stays in flight.
__device__ __forceinline__ void bar_lds(){ __asm__ volatile("s_waitcnt lgkmcnt(0)\n\ts_barrier" ::: "memory"); }

// ---------------- K1: xpre = C*(x@W1x + b1x + b1a), in k2's dup-4 slot order ----------------
// slot (8 bf16 = [nt1=0: r0..3][nt1=1: r0..3]) at u16 addr (((t*64+bg)*8 + w8)*16 + q*4 + b4)*8
// holds hidden cols w8*32 + nt1*16 + q*4 + r for batch bg*4 + b4.
__global__ __launch_bounds__(256, 1) void k1_xw(const float* __restrict__ x, const float* __restrict__ w1x,
                                               const float* __restrict__ b1x, const float* __restrict__ b1a,
                                               u16* __restrict__ xpre)
{
    const int t = blockIdx.x;
    const int tid = threadIdx.x, lane = tid & 63, w = tid >> 6;
    const int l15 = lane & 15, q = lane >> 4;
    const int cw = w * 64;

    bf16x8 bw[4][8];
    f32x4 biasv[4];
    #pragma unroll
    for (int nt = 0; nt < 4; ++nt){
        const int n0 = cw + nt * 16 + q * 4;
        f32x4 bx = *(const f32x4*)(b1x + n0);
        f32x4 ba = *(const f32x4*)(b1a + n0);
        biasv[nt] = (bx + ba) * C_TANH;
        const int n = cw + nt * 16 + l15;
        #pragma unroll
        for (int ks = 0; ks < 8; ++ks){
            u16x8 tt;
            #pragma unroll
            for (int j = 0; j < 8; ++j) tt[j] = f2b(w1x[(ks * 32 + q * 8 + j) * 256 + n] * C_TANH);
            bw[nt][ks] = __builtin_bit_cast(bf16x8, tt);
        }
    }

    for (int blk = 0; blk < 16; ++blk){
        const int b0r = blk * 16;
        bf16x8 av[8];
        #pragma unroll
        for (int ks = 0; ks < 8; ++ks){
            const float* p = x + ((size_t)(b0r + l15) * 512 + t) * 256 + ks * 32 + q * 8;
            f32x4 v0 = *(const f32x4*)p;
            f32x4 v1 = *(const f32x4*)(p + 4);
            u32x4 dd = { pkbf(v0[0], v0[1]), pkbf(v0[2], v0[3]),
                         pkbf(v1[0], v1[1]), pkbf(v1[2], v1[3]) };
            av[ks] = __builtin_bit_cast(bf16x8, dd);
        }
        f32x4 acc[4];
        #pragma unroll
        for (int nt = 0; nt < 4; ++nt) acc[nt] = biasv[nt];
        #pragma unroll
        for (int ks = 0; ks < 8; ++ks)
            #pragma unroll
            for (int nt = 0; nt < 4; ++nt)
                acc[nt] = MFMA16(bw[nt][ks], av[ks], acc[nt]);   // swapped: D[hidden][batch]
        const int bg = blk * 4 + (l15 >> 2), b4 = l15 & 3;
        #pragma unroll
        for (int p2 = 0; p2 < 2; ++p2){
            const size_t a16 = ((((size_t)t * 64 + bg) * 8 + (w * 2 + p2)) * 16 + q * 4 + b4) * 8;
            u32x4 V = { pkbf(acc[p2 * 2][0], acc[p2 * 2][1]), pkbf(acc[p2 * 2][2], acc[p2 * 2][3]),
                        pkbf(acc[p2 * 2 + 1][0], acc[p2 * 2 + 1][1]), pkbf(acc[p2 * 2 + 1][2], acc[p2 * 2 + 1][3]) };
            *(u32x4*)(xpre + a16) = V;
        }
    }
}

// ---------------- K2: encoder, 64 wgs x 512 thr (8 waves, 2/SIMD), dup-4 B-frags ----------------
__global__ __launch_bounds__(512, 2) void k2_enc(const float* __restrict__ w1a, const u16* __restrict__ xpre,
                                                u16* __restrict__ alast)
{
    __shared__ __align__(16) u16 st[2][4][272];
    const int tid = threadIdx.x, lane = tid & 63, w = tid >> 6;   // w 0..7, 32 hidden cols each
    const int l15 = lane & 15, q = lane >> 4;
    const int b4 = l15 & 3;
    const bool selnt = (l15 & 4) != 0, selrp = (l15 & 8) != 0;
    const int wcol = w * 32 + (selnt ? 16 : 0) + q * 4 + (selrp ? 2 : 0);
    const int bg = blockIdx.x;                     // 0..63, batches bg*4 .. bg*4+3

    bf16x8 bw[2][8];                               // C-scaled W1a as A-operand (32 cols), reg-resident
    #pragma unroll
    for (int nt = 0; nt < 2; ++nt){
        const int n = w * 32 + nt * 16 + l15;
        #pragma unroll
        for (int ks = 0; ks < 8; ++ks){
            u16x8 tt;
            #pragma unroll
            for (int j = 0; j < 8; ++j) tt[j] = f2b(w1a[(ks * 32 + q * 8 + j) * 256 + n] * C_TANH);
            bw[nt][ks] = __builtin_bit_cast(bf16x8, tt);
        }
    }
    for (int i = tid; i < 4 * 272; i += 512) (&st[0][0][0])[i] = 0;   // a0 = 0
    __syncthreads();

    // per-lane xpre slot: 8 bf16 = one dwordx4 per step (dup across l15>>2 groups)
    const u16* xp = xpre + (((size_t)bg * 8 + w) * 16 + q * 4 + b4) * 8;
    u32x4 c = *(const u32x4*)xp;
    u32x4 a = *(const u32x4*)(xp + 65536);

    const u16 (*sR)[272] = st[0];
    u16 (*sW)[272] = st[1];

    for (int t = 0; t < 512; ++t){
        const size_t tp = (size_t)((t + 2 < 512) ? t + 2 : 511) * 65536;
        u32x4 n_ = *(const u32x4*)(xp + tp);

        bf16x8 av[8];                              // B-operand: a[batch=b4][k]; 4-way broadcast
        #pragma unroll
        for (int ks = 0; ks < 8; ++ks)
            av[ks] = *(const bf16x8*)&sR[b4][ks * 32 + q * 8];

        f32x4 acc[2];                              // init = scaled xpre (identical across dup groups)
        #pragma unroll
        for (int nt = 0; nt < 2; ++nt)
            #pragma unroll
            for (int r = 0; r < 4; ++r){
                const u32 d = c[nt * 2 + (r >> 1)];
                acc[nt][r] = ubit((r & 1) ? (d & 0xFFFF0000u) : (d << 16));
            }
        #pragma unroll
        for (int ks = 0; ks < 8; ++ks)
            #pragma unroll
            for (int nt = 0; nt < 2; ++nt)
                acc[nt] = MFMA16(bw[nt][ks], av[ks], acc[nt]);   // swapped

        // each lane handles 2 real values: nt by l15 bit2, r-pair by bit3 (const-idx selects)
        const float s0 = selnt ? acc[1][0] : acc[0][0];
        const float s1 = selnt ? acc[1][1] : acc[0][1];
        const float s2 = selnt ? acc[1][2] : acc[0][2];
        const float s3 = selnt ? acc[1][3] : acc[0][3];
        const float mv0 = selrp ? s2 : s0;
        const float mv1 = selrp ? s3 : s1;
        const float e0 = __builtin_amdgcn_exp2f(mv0);
        const float t0 = 1.0f - 2.0f * __builtin_amdgcn_rcpf(e0 + 1.0f);
        const float e1 = __builtin_amdgcn_exp2f(mv1);
        const float t1 = 1.0f - 2.0f * __builtin_amdgcn_rcpf(e1 + 1.0f);
        *(u32*)&sW[b4][wcol] = pk_away(t0, t1);    // one b32 write, 2-way banked

        c = a; a = n_;
        bar_lds();                                   // LDS-only drain; vmem stays in flight
        const u16 (*tmp)[272] = sR; sR = (const u16(*)[272])sW; sW = (u16(*)[272])tmp;
    }
    if (tid < 128){
        const int row = tid >> 5, c8 = (tid & 31) * 8;
        *(u32x4*)(alast + (size_t)(bg * 4 + row) * 256 + c8) = *(const u32x4*)&sR[row][c8];
    }
}

// ---------------- K3pre: y0 = sigmoid(alast@Wy+by); inj = C*(y0@W2x) in k3a dup-4 slot order ----------------
__global__ __launch_bounds__(256, 1) void k3_pre(const float* __restrict__ wy, const float* __restrict__ by,
                                                const float* __restrict__ w2x,
                                                const u16* __restrict__ alast, float* __restrict__ injws)
{
    __shared__ __align__(16) u16 st[16][264];
    __shared__ __align__(16) u16 y0s[16][264];
    const int tid = threadIdx.x, lane = tid & 63, w = tid >> 6;
    const int l15 = lane & 15, q = lane >> 4;
    const int bg = blockIdx.x;                     // 0..15, batches bg*16 .. bg*16+15
    {
        const int row = tid >> 4, c = (tid & 15) * 16;
        #pragma unroll
        for (int j = 0; j < 2; ++j)
            *(u32x4*)&st[row][c + j * 8] = *(const u32x4*)(alast + (size_t)(bg * 16 + row) * 256 + c + j * 8);
    }
    __syncthreads();
    {   // y0 = sigm(alast@Wy+by), Wy scaled by -log2e; swapped -> wide b64 y0s writes
        bf16x8 bwy[4][8];
        f32x4 biasy[4];
        #pragma unroll
        for (int nt = 0; nt < 4; ++nt){
            const int n0 = w * 64 + nt * 16 + q * 4;
            biasy[nt] = (*(const f32x4*)(by + n0)) * NL2E;
            const int n = w * 64 + nt * 16 + l15;
            #pragma unroll
            for (int ks = 0; ks < 8; ++ks){
                u16x8 tt;
                #pragma unroll
                for (int j = 0; j < 8; ++j) tt[j] = f2b(wy[(ks * 32 + q * 8 + j) * 256 + n] * NL2E);
                bwy[nt][ks] = __builtin_bit_cast(bf16x8, tt);
            }
        }
        bf16x8 av[8];
        #pragma unroll
        for (int ks = 0; ks < 8; ++ks) av[ks] = *(const bf16x8*)&st[l15][ks * 32 + q * 8];
        f32x4 acc[4];
        #pragma unroll
        for (int nt = 0; nt < 4; ++nt) acc[nt] = biasy[nt];
        #pragma unroll
        for (int ks = 0; ks < 8; ++ks)
            #pragma unroll
            for (int nt = 0; nt < 4; ++nt) acc[nt] = MFMA16(bwy[nt][ks], av[ks], acc[nt]);
        #pragma unroll
        for (int nt = 0; nt < 4; ++nt){
            float y[4];
            #pragma unroll
            for (int r = 0; r < 4; ++r) y[r] = __builtin_amdgcn_rcpf(1.0f + __builtin_amdgcn_exp2f(acc[nt][r]));
            u32x2 hp = { pkbf(y[0], y[1]), pkbf(y[2], y[3]) };
            *(u32x2*)&y0s[l15][w * 64 + nt * 16 + q * 4] = hp;
        }
    }
    __syncthreads();
    {   // inj = C * (y0 @ W2x)  (no bias), stored in k3a's dup-4 per-lane slot order
        bf16x8 av[8];
        #pragma unroll
        for (int ks = 0; ks < 8; ++ks) av[ks] = *(const bf16x8*)&y0s[l15][ks * 32 + q * 8];
        f32x4 acc[4];
        #pragma unroll
        for (int nt = 0; nt < 4; ++nt) acc[nt] = (f32x4){0.f, 0.f, 0.f, 0.f};
        #pragma unroll
        for (int ks = 0; ks < 8; ++ks)
            #pragma unroll
            for (int nt = 0; nt < 4; ++nt){
                const int n = w * 64 + nt * 16 + l15;
                u16x8 tt;
                #pragma unroll
                for (int j = 0; j < 8; ++j) tt[j] = f2b(w2x[(ks * 32 + q * 8 + j) * 256 + n] * C_TANH);
                acc[nt] = MFMA16(__builtin_bit_cast(bf16x8, tt), av[ks], acc[nt]);
            }
        // k3a wg = bg*4 + (l15>>2), batch-in-wg b4 = l15&3, wave w8 = w*2+p2
        const int bgr = bg * 4 + (l15 >> 2), b4 = l15 & 3;
        #pragma unroll
        for (int p2 = 0; p2 < 2; ++p2){
            const size_t ib = (((size_t)bgr * 8 + (size_t)(w * 2 + p2)) * 16 + q * 4 + b4) * 8;
            *(f32x4*)(injws + ib)     = acc[p2 * 2];
            *(f32x4*)(injws + ib + 4) = acc[p2 * 2 + 1];
        }
    }
}

// ---------------- K3a: decoder recurrence, 64 wgs x 512 thr (8 waves, 2/SIMD), dup-4 ----------------
__global__ __launch_bounds__(512, 2) void k3_rec(const float* __restrict__ w2a, const float* __restrict__ b2x,
                                                const float* __restrict__ b2a, const u16* __restrict__ alast,
                                                const float* __restrict__ injws, u16* __restrict__ astate)
{
    __shared__ __align__(16) u16 st[2][4][272];
    const int tid = threadIdx.x, lane = tid & 63, w = tid >> 6;   // w 0..7
    const int l15 = lane & 15, q = lane >> 4;
    const int b4 = l15 & 3;
    const bool selnt = (l15 & 4) != 0, selrp = (l15 & 8) != 0;
    const int wcol = w * 32 + (selnt ? 16 : 0) + q * 4 + (selrp ? 2 : 0);
    const int bg = blockIdx.x;                     // 0..63

    bf16x8 bw[2][8];
    f32x4 bias2[2];
    #pragma unroll
    for (int nt = 0; nt < 2; ++nt){
        const int n0 = w * 32 + nt * 16 + q * 4;
        f32x4 bx = *(const f32x4*)(b2x + n0);
        f32x4 ba = *(const f32x4*)(b2a + n0);
        bias2[nt] = (bx + ba) * C_TANH;
        const int n = w * 32 + nt * 16 + l15;
        #pragma unroll
        for (int ks = 0; ks < 8; ++ks){
            u16x8 tt;
            #pragma unroll
            for (int j = 0; j < 8; ++j) tt[j] = f2b(w2a[(ks * 32 + q * 8 + j) * 256 + n] * C_TANH);
            bw[nt][ks] = __builtin_bit_cast(bf16x8, tt);
        }
    }
    f32x4 ini[2];
    {
        const size_t ib = (((size_t)bg * 8 + w) * 16 + q * 4 + b4) * 8;   // dup across l15>>2
        #pragma unroll
        for (int nt = 0; nt < 2; ++nt)
            ini[nt] = *(const f32x4*)(injws + ib + nt * 4) + bias2[nt];   // i==0 init; reset after
    }
    if (tid < 128){
        const int row = tid >> 5, c8 = (tid & 31) * 8;
        *(u32x4*)&st[0][row][c8] = *(const u32x4*)(alast + (size_t)(bg * 4 + row) * 256 + c8);
    }
    __syncthreads();

    const u16 (*sR)[272] = st[0];
    u16 (*sW)[272] = st[1];

    for (int i = 0; i < 64; ++i){
        bf16x8 av[8];
        #pragma unroll
        for (int ks = 0; ks < 8; ++ks) av[ks] = *(const bf16x8*)&sR[b4][ks * 32 + q * 8];
        f32x4 acc[2];
        #pragma unroll
        for (int nt = 0; nt < 2; ++nt) acc[nt] = ini[nt];
        #pragma unroll
        for (int ks = 0; ks < 8; ++ks)
            #pragma unroll
            for (int nt = 0; nt < 2; ++nt) acc[nt] = MFMA16(bw[nt][ks], av[ks], acc[nt]);

        const float s0 = selnt ? acc[1][0] : acc[0][0];
        const float s1 = selnt ? acc[1][1] : acc[0][1];
        const float s2 = selnt ? acc[1][2] : acc[0][2];
        const float s3 = selnt ? acc[1][3] : acc[0][3];
        const float mv0 = selrp ? s2 : s0;
        const float mv1 = selrp ? s3 : s1;
        const float e0 = __builtin_amdgcn_exp2f(mv0);
        const float t0 = 1.0f - 2.0f * __builtin_amdgcn_rcpf(e0 + 1.0f);
        const float e1 = __builtin_amdgcn_exp2f(mv1);
        const float t1 = 1.0f - 2.0f * __builtin_amdgcn_rcpf(e1 + 1.0f);
        const u32 hp = pk_away(t0, t1);
        *(u32*)&sW[b4][wcol] = hp;
        *(u32*)(astate + ((size_t)i * 256 + bg * 4 + b4) * 256 + wcol) = hp;  // vmem, not drained

        if (i == 0){
            #pragma unroll
            for (int nt = 0; nt < 2; ++nt) ini[nt] = bias2[nt];
        }
        bar_lds();
        const u16 (*tmp)[272] = sR; sR = (const u16(*)[272])sW; sW = (u16(*)[272])tmp;
    }
}

// ---------------- K3b: out = sigm(astate@Wy + by), wide f32x4 stores ----------------
__global__ __launch_bounds__(256, 1) void k3_out(const float* __restrict__ wy, const float* __restrict__ by,
                                                const u16* __restrict__ astate, float* __restrict__ out)
{
    const int tid = threadIdx.x, lane = tid & 63, w = tid >> 6;
    const int l15 = lane & 15, q = lane >> 4;

    bf16x8 bwy[4][8];
    f32x4 biasy[4];
    #pragma unroll
    for (int nt = 0; nt < 4; ++nt){
        const int n0 = w * 64 + nt * 16 + q * 4;
        biasy[nt] = (*(const f32x4*)(by + n0)) * NL2E;
        const int n = w * 64 + nt * 16 + l15;
        #pragma unroll
        for (int ks = 0; ks < 8; ++ks){
            u16x8 tt;
            #pragma unroll
            for (int j = 0; j < 8; ++j) tt[j] = f2b(wy[(ks * 32 + q * 8 + j) * 256 + n] * NL2E);
            bwy[nt][ks] = __builtin_bit_cast(bf16x8, tt);
        }
    }
    #pragma unroll
    for (int tix = 0; tix < 4; ++tix){
        const int R0 = (blockIdx.x * 4 + tix) * 16;          // flat row = i*256 + b
        bf16x8 av[8];
        #pragma unroll
        for (int ks = 0; ks < 8; ++ks)
            av[ks] = *(const bf16x8*)(astate + (size_t)(R0 + l15) * 256 + ks * 32 + q * 8);
        f32x4 acc[4];
        #pragma unroll
        for (int nt = 0; nt < 4; ++nt) acc[nt] = biasy[nt];
        #pragma unroll
        for (int ks = 0; ks < 8; ++ks)
            #pragma unroll
            for (int nt = 0; nt < 4; ++nt) acc[nt] = MFMA16(bwy[nt][ks], av[ks], acc[nt]);
        const int R = R0 + l15, ii = R >> 8, b = R & 255;
        #pragma unroll
        for (int nt = 0; nt < 4; ++nt){
            f32x4 o4;
            #pragma unroll
            for (int r = 0; r < 4; ++r)
                o4[r] = __builtin_amdgcn_rcpf(1.0f + __builtin_amdgcn_exp2f(acc[nt][r]));
            *(f32x4*)(out + ((size_t)b * 64 + ii) * 256 + w * 64 + nt * 16 + q * 4) = o4;
        }
    }
}

extern "C" void kernel_launch(void* const* d_in, const int* in_sizes, int n_in,
                              void* d_out, int out_size, void* d_ws, size_t ws_size,
                              hipStream_t stream) {
    const float* x   = (const float*)d_in[0];
    const float* w1x = (const float*)d_in[1];
    const float* b1x = (const float*)d_in[2];
    const float* w1a = (const float*)d_in[3];
    const float* b1a = (const float*)d_in[4];
    const float* w2x = (const float*)d_in[5];
    const float* b2x = (const float*)d_in[6];
    const float* w2a = (const float*)d_in[7];
    const float* b2a = (const float*)d_in[8];
    const float* wy  = (const float*)d_in[9];
    const float* by  = (const float*)d_in[10];

    u16*   xpre   = (u16*)d_ws;                     // 64 MiB (k1->k2), then reused:
    u16*   astate = (u16*)d_ws;                     // 8 MiB (k3a->k3b), aliases xpre (k2 done)
    u16*   alast  = xpre + (size_t)512 * 16 * 512 * 8;
    float* injws  = (float*)(alast + 256 * 256);    // 64K f32
    float* o      = (float*)d_out;

    k1_xw <<<512, 256, 0, stream>>>(x, w1x, b1x, b1a, xpre);
    k2_enc<<<64,  512, 0, stream>>>(w1a, xpre, alast);
    k3_pre<<<16,  256, 0, stream>>>(wy, by, w2x, alast, injws);
    k3_rec<<<64,  512, 0, stream>>>(w2a, b2x, b2a, alast, injws, astate);
    k3_out<<<256, 256, 0, stream>>>(wy, by, astate, o);
}

// Round 5
// 534.031 us; speedup vs baseline: 1.5526x; 1.0395x over previous
//
#include <hip/hip_runtime.h>

// B=256, S=512, I=H=O=256, L=64. fp32 in/out; bf16 MFMA internally.
// Operand-swapped MFMA everywhere: D = mfma(W_frag, a_frag) = D[hidden][batch].
// k2_full merges encoder + (y0,inj) + decoder in ONE kernel (64 wgs x 512 thr):
//   - alast stays in LDS; inj stays in REGISTERS (fragment layout == decoder ini)
//   - decoder astate goes into the xpre slots this wg owns and already consumed
//     (slot i*64+bg, i<64 << t) -> no cross-wg aliasing despite ws reuse.
// dup-4 structure as round 4: 4 batch rows/wg, 8 waves (2/SIMD) x 32 hidden cols,
// B-operand 4x column-duplicated -> 2 tanh values/lane, b32 state writes.
typedef unsigned short u16;
typedef unsigned int   u32;
typedef __attribute__((ext_vector_type(8))) __bf16 bf16x8;
typedef __attribute__((ext_vector_type(8))) u16    u16x8;
typedef __attribute__((ext_vector_type(4))) float  f32x4;
typedef __attribute__((ext_vector_type(4))) u32    u32x4;
typedef __attribute__((ext_vector_type(2))) u32    u32x2;

#define MFMA16(a,b,c) __builtin_amdgcn_mfma_f32_16x16x32_bf16((a),(b),(c),0,0,0)
#define C_TANH 2.8853900817779268f   /* 2*log2(e): tanh(v)=1-2/(2^(C*v)+1) */
#define NL2E  -1.4426950408889634f   /* -log2(e): sigm(u)=1/(1+2^(NL2E*u)) */

__device__ __forceinline__ float ubit(u32 x){ return __builtin_bit_cast(float, x); }
__device__ __forceinline__ u16 f2b(float f){ // RNE f32->bf16 (prep paths)
    u32 b = __builtin_bit_cast(u32, f);
    b += 0x7FFFu + ((b >> 16) & 1u);
    return (u16)(b >> 16);
}
__device__ __forceinline__ u32 pkbf(float a, float b){ return ((u32)f2b(b) << 16) | (u32)f2b(a); }
__device__ __forceinline__ u32 pk_away(float a, float b){ // round-away pack (state path)
    u32 ua = (__builtin_bit_cast(u32, a) + 0x8000u) >> 16;
    u32 ub = (__builtin_bit_cast(u32, b) + 0x8000u) & 0xFFFF0000u;
    return ub | ua;
}
// Barrier that drains ONLY LDS counters -- vmem (prefetch/stores) stays in flight.
__device__ __forceinline__ void bar_lds(){ __asm__ volatile("s_waitcnt lgkmcnt(0)\n\ts_barrier" ::: "memory"); }

// ---------------- K1: xpre = C*(x@W1x + b1x + b1a), in k2's dup-4 slot order ----------------
// slot (8 bf16 = [nt1=0: r0..3][nt1=1: r0..3]) at u16 addr (((t*64+bg)*8 + w8)*16 + q*4 + b4)*8
__global__ __launch_bounds__(256, 1) void k1_xw(const float* __restrict__ x, const float* __restrict__ w1x,
                                               const float* __restrict__ b1x, const float* __restrict__ b1a,
                                               u16* __restrict__ xpre)
{
    const int t = blockIdx.x;
    const int tid = threadIdx.x, lane = tid & 63, w = tid >> 6;
    const int l15 = lane & 15, q = lane >> 4;
    const int cw = w * 64;

    bf16x8 bw[4][8];
    f32x4 biasv[4];
    #pragma unroll
    for (int nt = 0; nt < 4; ++nt){
        const int n0 = cw + nt * 16 + q * 4;
        f32x4 bx = *(const f32x4*)(b1x + n0);
        f32x4 ba = *(const f32x4*)(b1a + n0);
        biasv[nt] = (bx + ba) * C_TANH;
        const int n = cw + nt * 16 + l15;
        #pragma unroll
        for (int ks = 0; ks < 8; ++ks){
            u16x8 tt;
            #pragma unroll
            for (int j = 0; j < 8; ++j) tt[j] = f2b(w1x[(ks * 32 + q * 8 + j) * 256 + n] * C_TANH);
            bw[nt][ks] = __builtin_bit_cast(bf16x8, tt);
        }
    }

    for (int blk = 0; blk < 16; ++blk){
        const int b0r = blk * 16;
        bf16x8 av[8];
        #pragma unroll
        for (int ks = 0; ks < 8; ++ks){
            const float* p = x + ((size_t)(b0r + l15) * 512 + t) * 256 + ks * 32 + q * 8;
            f32x4 v0 = *(const f32x4*)p;
            f32x4 v1 = *(const f32x4*)(p + 4);
            u32x4 dd = { pkbf(v0[0], v0[1]), pkbf(v0[2], v0[3]),
                         pkbf(v1[0], v1[1]), pkbf(v1[2], v1[3]) };
            av[ks] = __builtin_bit_cast(bf16x8, dd);
        }
        f32x4 acc[4];
        #pragma unroll
        for (int nt = 0; nt < 4; ++nt) acc[nt] = biasv[nt];
        #pragma unroll
        for (int ks = 0; ks < 8; ++ks)
            #pragma unroll
            for (int nt = 0; nt < 4; ++nt)
                acc[nt] = MFMA16(bw[nt][ks], av[ks], acc[nt]);   // swapped: D[hidden][batch]
        const int bg = blk * 4 + (l15 >> 2), b4 = l15 & 3;
        #pragma unroll
        for (int p2 = 0; p2 < 2; ++p2){
            const size_t a16 = ((((size_t)t * 64 + bg) * 8 + (w * 2 + p2)) * 16 + q * 4 + b4) * 8;
            u32x4 V = { pkbf(acc[p2 * 2][0], acc[p2 * 2][1]), pkbf(acc[p2 * 2][2], acc[p2 * 2][3]),
                        pkbf(acc[p2 * 2 + 1][0], acc[p2 * 2 + 1][1]), pkbf(acc[p2 * 2 + 1][2], acc[p2 * 2 + 1][3]) };
            *(u32x4*)(xpre + a16) = V;
        }
    }
}

// ---------------- K2_full: encoder + y0/inj + decoder, 64 wgs x 512 thr ----------------
__global__ __launch_bounds__(512, 2) void k2_full(const float* __restrict__ w1a, const float* __restrict__ wy,
                                                 const float* __restrict__ by,  const float* __restrict__ w2x,
                                                 const float* __restrict__ w2a, const float* __restrict__ b2x,
                                                 const float* __restrict__ b2a, u16* ws)
{
    __shared__ __align__(16) u16 st[2][4][272];
    const int tid = threadIdx.x, lane = tid & 63, w = tid >> 6;   // w 0..7, 32 hidden cols each
    const int l15 = lane & 15, q = lane >> 4;
    const int b4 = l15 & 3;
    const bool selnt = (l15 & 4) != 0, selrp = (l15 & 8) != 0;
    const int wcol = w * 32 + (selnt ? 16 : 0) + q * 4 + (selrp ? 2 : 0);
    const int bg = blockIdx.x;                     // 0..63, batches bg*4 .. bg*4+3

    bf16x8 bw[2][8];                               // C-scaled W1a as A-operand (32 cols), reg-resident
    #pragma unroll
    for (int nt = 0; nt < 2; ++nt){
        const int n = w * 32 + nt * 16 + l15;
        #pragma unroll
        for (int ks = 0; ks < 8; ++ks){
            u16x8 tt;
            #pragma unroll
            for (int j = 0; j < 8; ++j) tt[j] = f2b(w1a[(ks * 32 + q * 8 + j) * 256 + n] * C_TANH);
            bw[nt][ks] = __builtin_bit_cast(bf16x8, tt);
        }
    }
    for (int i = tid; i < 4 * 272; i += 512) (&st[0][0][0])[i] = 0;   // a0 = 0
    __syncthreads();

    // per-lane xpre slot: 8 bf16 = one dwordx4 per step (dup across l15>>2 groups)
    const u16* xp = ws + (((size_t)bg * 8 + w) * 16 + q * 4 + b4) * 8;
    u32x4 c = *(const u32x4*)xp;
    u32x4 a = *(const u32x4*)(xp + 65536);

    const u16 (*sR)[272] = st[0];
    u16 (*sW)[272] = st[1];

    // ============ Phase E: encoder, 512 steps ============
    for (int t = 0; t < 512; ++t){
        const size_t tp = (size_t)((t + 2 < 512) ? t + 2 : 511) * 65536;
        u32x4 n_ = *(const u32x4*)(xp + tp);

        bf16x8 av[8];                              // B-operand: a[batch=b4][k]; 4-way broadcast
        #pragma unroll
        for (int ks = 0; ks < 8; ++ks)
            av[ks] = *(const bf16x8*)&sR[b4][ks * 32 + q * 8];

        f32x4 acc[2];                              // init = scaled xpre (identical across dup groups)
        #pragma unroll
        for (int nt = 0; nt < 2; ++nt)
            #pragma unroll
            for (int r = 0; r < 4; ++r){
                const u32 d = c[nt * 2 + (r >> 1)];
                acc[nt][r] = ubit((r & 1) ? (d & 0xFFFF0000u) : (d << 16));
            }
        __builtin_amdgcn_s_setprio(1);
        #pragma unroll
        for (int ks = 0; ks < 8; ++ks)
            #pragma unroll
            for (int nt = 0; nt < 2; ++nt)
                acc[nt] = MFMA16(bw[nt][ks], av[ks], acc[nt]);   // swapped
        __builtin_amdgcn_s_setprio(0);

        // each lane handles 2 real values: nt by l15 bit2, r-pair by bit3
        const float s0 = selnt ? acc[1][0] : acc[0][0];
        const float s1 = selnt ? acc[1][1] : acc[0][1];
        const float s2 = selnt ? acc[1][2] : acc[0][2];
        const float s3 = selnt ? acc[1][3] : acc[0][3];
        const float mv0 = selrp ? s2 : s0;
        const float mv1 = selrp ? s3 : s1;
        const float e0 = __builtin_amdgcn_exp2f(mv0);
        const float t0 = 1.0f - 2.0f * __builtin_amdgcn_rcpf(e0 + 1.0f);
        const float e1 = __builtin_amdgcn_exp2f(mv1);
        const float t1 = 1.0f - 2.0f * __builtin_amdgcn_rcpf(e1 + 1.0f);
        *(u32*)&sW[b4][wcol] = pk_away(t0, t1);

        c = a; a = n_;
        bar_lds();                                   // LDS-only drain; vmem stays in flight
        const u16 (*tmp)[272] = sR; sR = (const u16(*)[272])sW; sW = (u16(*)[272])tmp;
    }
    // sR now holds alast (4 batches x 256 bf16) in LDS.

    // ============ Phase P: y0 = sigm(alast@Wy+by); inj = C*(y0@W2x) in regs ============
    {
        bf16x8 bwy[2][8];
        f32x4 biasy[2];
        #pragma unroll
        for (int nt = 0; nt < 2; ++nt){
            const int n0 = w * 32 + nt * 16 + q * 4;
            biasy[nt] = (*(const f32x4*)(by + n0)) * NL2E;
            const int n = w * 32 + nt * 16 + l15;
            #pragma unroll
            for (int ks = 0; ks < 8; ++ks){
                u16x8 tt;
                #pragma unroll
                for (int j = 0; j < 8; ++j) tt[j] = f2b(wy[(ks * 32 + q * 8 + j) * 256 + n] * NL2E);
                bwy[nt][ks] = __builtin_bit_cast(bf16x8, tt);
            }
        }
        bf16x8 av[8];
        #pragma unroll
        for (int ks = 0; ks < 8; ++ks) av[ks] = *(const bf16x8*)&sR[b4][ks * 32 + q * 8];
        f32x4 acc[2];
        #pragma unroll
        for (int nt = 0; nt < 2; ++nt) acc[nt] = biasy[nt];
        #pragma unroll
        for (int ks = 0; ks < 8; ++ks)
            #pragma unroll
            for (int nt = 0; nt < 2; ++nt) acc[nt] = MFMA16(bwy[nt][ks], av[ks], acc[nt]);
        const float s0 = selnt ? acc[1][0] : acc[0][0];
        const float s1 = selnt ? acc[1][1] : acc[0][1];
        const float s2 = selnt ? acc[1][2] : acc[0][2];
        const float s3 = selnt ? acc[1][3] : acc[0][3];
        const float mv0 = selrp ? s2 : s0;
        const float mv1 = selrp ? s3 : s1;
        const float y0v = __builtin_amdgcn_rcpf(1.0f + __builtin_amdgcn_exp2f(mv0));
        const float y1v = __builtin_amdgcn_rcpf(1.0f + __builtin_amdgcn_exp2f(mv1));
        *(u32*)&sW[b4][wcol] = pkbf(y0v, y1v);     // y0 into the free buffer
    }
    bar_lds();

    f32x4 ini[2];                                  // decoder i==0 init, stays in registers
    f32x4 bias2[2];
    {
        bf16x8 av2[8];
        #pragma unroll
        for (int ks = 0; ks < 8; ++ks) av2[ks] = *(const bf16x8*)&sW[b4][ks * 32 + q * 8];
        bar_lds();                                 // all y0 reads done; decoder may overwrite sW
        #pragma unroll
        for (int nt = 0; nt < 2; ++nt){
            const int n0 = w * 32 + nt * 16 + q * 4;
            f32x4 bx = *(const f32x4*)(b2x + n0);
            f32x4 ba = *(const f32x4*)(b2a + n0);
            bias2[nt] = (bx + ba) * C_TANH;
            ini[nt] = (f32x4){0.f, 0.f, 0.f, 0.f};
        }
        #pragma unroll
        for (int ks = 0; ks < 8; ++ks)
            #pragma unroll
            for (int nt = 0; nt < 2; ++nt){
                const int n = w * 32 + nt * 16 + l15;
                u16x8 tt;
                #pragma unroll
                for (int j = 0; j < 8; ++j) tt[j] = f2b(w2x[(ks * 32 + q * 8 + j) * 256 + n] * C_TANH);
                ini[nt] = MFMA16(__builtin_bit_cast(bf16x8, tt), av2[ks], ini[nt]);
            }
        #pragma unroll
        for (int nt = 0; nt < 2; ++nt) ini[nt] = ini[nt] + bias2[nt];
        // re-prep bw with C-scaled W2a (encoder weights dead)
        #pragma unroll
        for (int nt = 0; nt < 2; ++nt){
            const int n = w * 32 + nt * 16 + l15;
            #pragma unroll
            for (int ks = 0; ks < 8; ++ks){
                u16x8 tt;
                #pragma unroll
                for (int j = 0; j < 8; ++j) tt[j] = f2b(w2a[(ks * 32 + q * 8 + j) * 256 + n] * C_TANH);
                bw[nt][ks] = __builtin_bit_cast(bf16x8, tt);
            }
        }
    }

    // ============ Phase D: decoder, 64 steps; astate into own consumed xpre slots ============
    for (int i = 0; i < 64; ++i){
        bf16x8 av[8];
        #pragma unroll
        for (int ks = 0; ks < 8; ++ks) av[ks] = *(const bf16x8*)&sR[b4][ks * 32 + q * 8];
        f32x4 acc[2];
        #pragma unroll
        for (int nt = 0; nt < 2; ++nt) acc[nt] = ini[nt];
        __builtin_amdgcn_s_setprio(1);
        #pragma unroll
        for (int ks = 0; ks < 8; ++ks)
            #pragma unroll
            for (int nt = 0; nt < 2; ++nt) acc[nt] = MFMA16(bw[nt][ks], av[ks], acc[nt]);
        __builtin_amdgcn_s_setprio(0);

        const float s0 = selnt ? acc[1][0] : acc[0][0];
        const float s1 = selnt ? acc[1][1] : acc[0][1];
        const float s2 = selnt ? acc[1][2] : acc[0][2];
        const float s3 = selnt ? acc[1][3] : acc[0][3];
        const float mv0 = selrp ? s2 : s0;
        const float mv1 = selrp ? s3 : s1;
        const float e0 = __builtin_amdgcn_exp2f(mv0);
        const float t0 = 1.0f - 2.0f * __builtin_amdgcn_rcpf(e0 + 1.0f);
        const float e1 = __builtin_amdgcn_exp2f(mv1);
        const float t1 = 1.0f - 2.0f * __builtin_amdgcn_rcpf(e1 + 1.0f);
        const u32 hp = pk_away(t0, t1);
        *(u32*)&sW[b4][wcol] = hp;
        // astate slot (i*64+bg): owned by this wg, consumed by its encoder long ago
        *(u32*)(ws + (((size_t)(i * 64 + bg)) << 10) + b4 * 256 + wcol) = hp;

        if (i == 0){
            #pragma unroll
            for (int nt = 0; nt < 2; ++nt) ini[nt] = bias2[nt];
        }
        bar_lds();
        const u16 (*tmp)[272] = sR; sR = (const u16(*)[272])sW; sW = (u16(*)[272])tmp;
    }
}

// ---------------- K3b: out = sigm(astate@Wy + by), wide f32x4 stores ----------------
__global__ __launch_bounds__(256, 1) void k3_out(const float* __restrict__ wy, const float* __restrict__ by,
                                                const u16* __restrict__ astate, float* __restrict__ out)
{
    const int tid = threadIdx.x, lane = tid & 63, w = tid >> 6;
    const int l15 = lane & 15, q = lane >> 4;

    bf16x8 bwy[4][8];
    f32x4 biasy[4];
    #pragma unroll
    for (int nt = 0; nt < 4; ++nt){
        const int n0 = w * 64 + nt * 16 + q * 4;
        biasy[nt] = (*(const f32x4*)(by + n0)) * NL2E;
        const int n = w * 64 + nt * 16 + l15;
        #pragma unroll
        for (int ks = 0; ks < 8; ++ks){
            u16x8 tt;
            #pragma unroll
            for (int j = 0; j < 8; ++j) tt[j] = f2b(wy[(ks * 32 + q * 8 + j) * 256 + n] * NL2E);
            bwy[nt][ks] = __builtin_bit_cast(bf16x8, tt);
        }
    }
    #pragma unroll
    for (int tix = 0; tix < 4; ++tix){
        const int R0 = (blockIdx.x * 4 + tix) * 16;          // flat row = i*256 + b
        const int Rl = R0 + l15, iiL = Rl >> 8, bL = Rl & 255;
        const u16* ap = astate + (((size_t)(iiL * 64 + (bL >> 2))) << 10) + (size_t)(bL & 3) * 256;
        bf16x8 av[8];
        #pragma unroll
        for (int ks = 0; ks < 8; ++ks)
            av[ks] = *(const bf16x8*)(ap + ks * 32 + q * 8);
        f32x4 acc[4];
        #pragma unroll
        for (int nt = 0; nt < 4; ++nt) acc[nt] = biasy[nt];
        #pragma unroll
        for (int ks = 0; ks < 8; ++ks)
            #pragma unroll
            for (int nt = 0; nt < 4; ++nt) acc[nt] = MFMA16(bwy[nt][ks], av[ks], acc[nt]);
        #pragma unroll
        for (int nt = 0; nt < 4; ++nt){
            f32x4 o4;
            #pragma unroll
            for (int r = 0; r < 4; ++r)
                o4[r] = __builtin_amdgcn_rcpf(1.0f + __builtin_amdgcn_exp2f(acc[nt][r]));
            *(f32x4*)(out + ((size_t)bL * 64 + iiL) * 256 + w * 64 + nt * 16 + q * 4) = o4;
        }
    }
}

extern "C" void kernel_launch(void* const* d_in, const int* in_sizes, int n_in,
                              void* d_out, int out_size, void* d_ws, size_t ws_size,
                              hipStream_t stream) {
    const float* x   = (const float*)d_in[0];
    const float* w1x = (const float*)d_in[1];
    const float* b1x = (const float*)d_in[2];
    const float* w1a = (const float*)d_in[3];
    const float* b1a = (const float*)d_in[4];
    const float* w2x = (const float*)d_in[5];
    const float* b2x = (const float*)d_in[6];
    const float* w2a = (const float*)d_in[7];
    const float* b2a = (const float*)d_in[8];
    const float* wy  = (const float*)d_in[9];
    const float* by  = (const float*)d_in[10];

    u16*   ws16 = (u16*)d_ws;       // 64 MiB xpre; decoder reuses per-wg consumed slots for astate
    float* o    = (float*)d_out;

    k1_xw  <<<512, 256, 0, stream>>>(x, w1x, b1x, b1a, ws16);
    k2_full<<<64,  512, 0, stream>>>(w1a, wy, by, w2x, w2a, b2x, b2a, ws16);
    k3_out <<<256, 256, 0, stream>>>(wy, by, ws16, o);
}